// Round 1
// baseline (3506.875 us; speedup 1.0000x reference)
//
#include <hip/hip_runtime.h>
#include <hip/hip_bf16.h>

constexpr int B = 64, S = 197, HID = 768, NH = 12, DH = 64;
constexpr int M = B * S;           // 12608 = 64*197
constexpr int BNS = B * NH * S;    // 151296
#define EPSC 1e-24f

// ---------------- GEMM: Y = act(X @ W + bias) ----------------
// X: [M, HID] f32 row-major; W: [HID(in), HID(out)] f32 row-major; bias [HID]
// MODE 0: linear; MODE 1: elu(x)+1 = (x>0 ? x+1 : exp(x))
// OUT_BF16 1: write bf16, else f32
template <int MODE, int OUT_BF16>
__global__ __launch_bounds__(256) void gemm_kernel(
    const float* __restrict__ X, const float* __restrict__ W,
    const float* __restrict__ bias, void* __restrict__ Yv) {
  __shared__ alignas(16) float As[16][68];  // [k][m], padded
  __shared__ alignas(16) float Bs[16][64];  // [k][n]
  const int m0 = blockIdx.x * 64;
  const int n0 = blockIdx.y * 64;
  const int tid = threadIdx.x;
  const int tx = tid & 15, ty = tid >> 4;

  float acc[4][4] = {};

  for (int k0 = 0; k0 < HID; k0 += 16) {
    {  // A tile: 64 rows x 16 cols, one float4 per thread
      const int r = tid >> 2, c4 = (tid & 3) * 4;
      const float4 a = *reinterpret_cast<const float4*>(
          &X[(size_t)(m0 + r) * HID + k0 + c4]);
      As[c4 + 0][r] = a.x;
      As[c4 + 1][r] = a.y;
      As[c4 + 2][r] = a.z;
      As[c4 + 3][r] = a.w;
    }
    {  // B tile: 16 rows x 64 cols
      const int r = tid >> 4, c4 = (tid & 15) * 4;
      *reinterpret_cast<float4*>(&Bs[r][c4]) =
          *reinterpret_cast<const float4*>(&W[(size_t)(k0 + r) * HID + n0 + c4]);
    }
    __syncthreads();
#pragma unroll
    for (int k = 0; k < 16; ++k) {
      const float4 a4 = *reinterpret_cast<const float4*>(&As[k][ty * 4]);
      const float4 b4 = *reinterpret_cast<const float4*>(&Bs[k][tx * 4]);
      const float a[4] = {a4.x, a4.y, a4.z, a4.w};
      const float bb[4] = {b4.x, b4.y, b4.z, b4.w};
#pragma unroll
      for (int i = 0; i < 4; ++i)
#pragma unroll
        for (int j = 0; j < 4; ++j) acc[i][j] = fmaf(a[i], bb[j], acc[i][j]);
    }
    __syncthreads();
  }

#pragma unroll
  for (int j = 0; j < 4; ++j) {
    const float bv = bias[n0 + tx * 4 + j];
#pragma unroll
    for (int i = 0; i < 4; ++i) {
      float v = acc[i][j] + bv;
      if (MODE == 1) v = (v > 0.0f) ? v + 1.0f : __expf(v);
      const size_t idx = (size_t)(m0 + ty * 4 + i) * HID + n0 + tx * 4 + j;
      if (OUT_BF16)
        reinterpret_cast<__hip_bfloat16*>(Yv)[idx] = __float2bfloat16(v);
      else
        reinterpret_cast<float*>(Yv)[idx] = v;
    }
  }
}

// ---------------- per-(b,h,s) sums: m2 = sum(m^2), csum = sum(c) ----------
__global__ __launch_bounds__(256) void sums_kernel(
    const __hip_bfloat16* __restrict__ mq, const __hip_bfloat16* __restrict__ cq,
    const __hip_bfloat16* __restrict__ mk, const __hip_bfloat16* __restrict__ ck,
    float* __restrict__ m2q, float* __restrict__ cqsum,
    float* __restrict__ m2k, float* __restrict__ cksum) {
  const int w = threadIdx.x >> 6, lane = threadIdx.x & 63;
  const int t = blockIdx.x * 4 + w;  // grid sized exactly: t < BNS
  const int b = t / (NH * S);
  const int rem = t - b * (NH * S);
  const int h = rem / S;
  const int s = rem - h * S;
  const size_t idx = (size_t)(b * S + s) * HID + h * DH + lane;
  const float vmq = __bfloat162float(mq[idx]);
  const float vcq = __bfloat162float(cq[idx]);
  const float vmk = __bfloat162float(mk[idx]);
  const float vck = __bfloat162float(ck[idx]);
  float a = vmq * vmq, bq = vcq, c = vmk * vmk, d = vck;
#pragma unroll
  for (int off = 32; off; off >>= 1) {
    a += __shfl_down(a, off, 64);
    bq += __shfl_down(bq, off, 64);
    c += __shfl_down(c, off, 64);
    d += __shfl_down(d, off, 64);
  }
  if (lane == 0) {
    const int o = (b * NH + h) * S + s;
    m2q[o] = a;
    cqsum[o] = bq;
    m2k[o] = c;
    cksum[o] = d;
  }
}

// ---------------- fused Wasserstein attention ----------------
// one block = one (b, h, 32-row Q tile); 256 threads = 4 waves
__global__ __launch_bounds__(256) void attn_kernel(
    const __hip_bfloat16* __restrict__ mq, const __hip_bfloat16* __restrict__ cq,
    const __hip_bfloat16* __restrict__ mk, const __hip_bfloat16* __restrict__ ck,
    const __hip_bfloat16* __restrict__ mv, const __hip_bfloat16* __restrict__ cv,
    const float* __restrict__ m2q, const float* __restrict__ cqsum,
    const float* __restrict__ m2k, const float* __restrict__ cksum,
    float* __restrict__ mean_ctx, float* __restrict__ cov_ctx) {
  __shared__ alignas(16) float mqs[32][68];
  __shared__ alignas(16) float sqs[32][68];   // sqrt(cov_q)
  __shared__ alignas(16) float kb0[64][68];   // mean_k  | mean_v
  __shared__ alignas(16) float kb1[64][68];   // sqrt(cov_k) | cov_v
  __shared__ float probs[32][201];
  __shared__ float qm2s[32], qcss[32], km2s[64], kcss[64];

  const int b = blockIdx.z, h = blockIdx.y;
  const int s0 = blockIdx.x * 32;
  const int tid = threadIdx.x;
  const int w = tid >> 6, lane = tid & 63;

  // ---- stage Q tile ----
#pragma unroll
  for (int t = 0; t < 8; ++t) {
    const int lin = tid + t * 256;
    const int i = lin >> 6, d = lin & 63;
    const int s = s0 + i;
    float vm = 0.f, vs = 0.f;
    if (s < S) {
      const size_t idx = (size_t)(b * S + s) * HID + h * DH + d;
      vm = __bfloat162float(mq[idx]);
      vs = sqrtf(fmaxf(__bfloat162float(cq[idx]), EPSC));
    }
    mqs[i][d] = vm;
    sqs[i][d] = vs;
  }
  if (tid < 32) {
    const int s = s0 + tid;
    const int o = (b * NH + h) * S + s;
    qm2s[tid] = (s < S) ? m2q[o] : 0.f;
    qcss[tid] = (s < S) ? cqsum[o] : 0.f;
  }
  __syncthreads();

  // ---- scores: probs[i][col] = -(wasserstein)/8 ----
  for (int kt = 0; kt < 4; ++kt) {
    const int k0 = kt * 64;
#pragma unroll
    for (int t = 0; t < 16; ++t) {
      const int lin = tid + t * 256;
      const int j = lin >> 6, d = lin & 63;
      const int s = k0 + j;
      float vm = 0.f, vs = 0.f;
      if (s < S) {
        const size_t idx = (size_t)(b * S + s) * HID + h * DH + d;
        vm = __bfloat162float(mk[idx]);
        vs = sqrtf(fmaxf(__bfloat162float(ck[idx]), EPSC));
      }
      kb0[j][d] = vm;
      kb1[j][d] = vs;
    }
    if (tid < 64) {
      const int s = k0 + tid;
      const int o = (b * NH + h) * S + s;
      km2s[tid] = (s < S) ? m2k[o] : 0.f;
      kcss[tid] = (s < S) ? cksum[o] : 0.f;
    }
    __syncthreads();

    const int j = lane;
    const int col = k0 + j;
#pragma unroll
    for (int p = 0; p < 4; ++p) {
      const int i0 = w * 8 + p * 2, i1 = i0 + 1;
      float dm0 = 0.f, dm1 = 0.f, dc0 = 0.f, dc1 = 0.f;
#pragma unroll
      for (int d4 = 0; d4 < 64; d4 += 4) {
        const float4 km = *reinterpret_cast<const float4*>(&kb0[j][d4]);
        const float4 ks = *reinterpret_cast<const float4*>(&kb1[j][d4]);
        const float4 qa = *reinterpret_cast<const float4*>(&mqs[i0][d4]);
        const float4 qb = *reinterpret_cast<const float4*>(&mqs[i1][d4]);
        const float4 sa = *reinterpret_cast<const float4*>(&sqs[i0][d4]);
        const float4 sb = *reinterpret_cast<const float4*>(&sqs[i1][d4]);
        dm0 = fmaf(qa.x, km.x, fmaf(qa.y, km.y, fmaf(qa.z, km.z, fmaf(qa.w, km.w, dm0))));
        dm1 = fmaf(qb.x, km.x, fmaf(qb.y, km.y, fmaf(qb.z, km.z, fmaf(qb.w, km.w, dm1))));
        dc0 = fmaf(sa.x, ks.x, fmaf(sa.y, ks.y, fmaf(sa.z, ks.z, fmaf(sa.w, ks.w, dc0))));
        dc1 = fmaf(sb.x, ks.x, fmaf(sb.y, ks.y, fmaf(sb.z, ks.z, fmaf(sb.w, ks.w, dc1))));
      }
      const float kmc = km2s[j] + kcss[j];
      const float sc0 = -(qm2s[i0] + qcss[i0] + kmc - 2.f * (dm0 + dc0)) * 0.125f;
      const float sc1 = -(qm2s[i1] + qcss[i1] + kmc - 2.f * (dm1 + dc1)) * 0.125f;
      if (col < 201) {
        probs[i0][col] = (col < S) ? sc0 : -1e30f;
        probs[i1][col] = (col < S) ? sc1 : -1e30f;
      }
    }
    __syncthreads();
  }

  // ---- softmax: wave w owns rows w*8..w*8+7 (same rows it wrote) ----
#pragma unroll
  for (int it = 0; it < 8; ++it) {
    const int i = w * 8 + it;
    float mx = -1e30f;
    for (int c = lane; c < 201; c += 64) mx = fmaxf(mx, probs[i][c]);
#pragma unroll
    for (int off = 32; off; off >>= 1) mx = fmaxf(mx, __shfl_down(mx, off, 64));
    mx = __shfl(mx, 0, 64);
    float sum = 0.f;
    for (int c = lane; c < 201; c += 64) {
      const float e = __expf(probs[i][c] - mx);
      probs[i][c] = e;
      sum += e;
    }
#pragma unroll
    for (int off = 32; off; off >>= 1) sum += __shfl_down(sum, off, 64);
    sum = __shfl(sum, 0, 64);
    const float inv = 1.0f / sum;
    for (int c = lane; c < 201; c += 64) probs[i][c] *= inv;
  }
  __syncthreads();

  // ---- PV: mean_ctx = P @ mean_v ; cov_ctx = (P*P) @ cov_v ----
  const int dg = tid & 15, ro = tid >> 4;  // thread owns rows {ro, ro+16}, dims dg*4..+3
  float4 am0 = {0, 0, 0, 0}, am1 = {0, 0, 0, 0};
  float4 ac0 = {0, 0, 0, 0}, ac1 = {0, 0, 0, 0};
  for (int kt = 0; kt < 4; ++kt) {
    const int k0 = kt * 64;
    const int jend = min(64, S - k0);
#pragma unroll
    for (int t = 0; t < 16; ++t) {
      const int lin = tid + t * 256;
      const int j = lin >> 6, d = lin & 63;
      const int s = k0 + j;
      float vm = 0.f, vc = 0.f;
      if (s < S) {
        const size_t idx = (size_t)(b * S + s) * HID + h * DH + d;
        vm = __bfloat162float(mv[idx]);
        vc = __bfloat162float(cv[idx]);
      }
      kb0[j][d] = vm;
      kb1[j][d] = vc;
    }
    __syncthreads();
    for (int j = 0; j < jend; ++j) {
      const float p0 = probs[ro][k0 + j];
      const float p1 = probs[ro + 16][k0 + j];
      const float4 vm = *reinterpret_cast<const float4*>(&kb0[j][dg * 4]);
      const float4 vc = *reinterpret_cast<const float4*>(&kb1[j][dg * 4]);
      am0.x = fmaf(p0, vm.x, am0.x); am0.y = fmaf(p0, vm.y, am0.y);
      am0.z = fmaf(p0, vm.z, am0.z); am0.w = fmaf(p0, vm.w, am0.w);
      am1.x = fmaf(p1, vm.x, am1.x); am1.y = fmaf(p1, vm.y, am1.y);
      am1.z = fmaf(p1, vm.z, am1.z); am1.w = fmaf(p1, vm.w, am1.w);
      const float q0 = p0 * p0, q1 = p1 * p1;
      ac0.x = fmaf(q0, vc.x, ac0.x); ac0.y = fmaf(q0, vc.y, ac0.y);
      ac0.z = fmaf(q0, vc.z, ac0.z); ac0.w = fmaf(q0, vc.w, ac0.w);
      ac1.x = fmaf(q1, vc.x, ac1.x); ac1.y = fmaf(q1, vc.y, ac1.y);
      ac1.z = fmaf(q1, vc.z, ac1.z); ac1.w = fmaf(q1, vc.w, ac1.w);
    }
    __syncthreads();
  }
  {
    const int sa = s0 + ro, sb = s0 + ro + 16;
    if (sa < S) {
      const size_t idx = (size_t)(b * S + sa) * HID + h * DH + dg * 4;
      *reinterpret_cast<float4*>(&mean_ctx[idx]) = am0;
      *reinterpret_cast<float4*>(&cov_ctx[idx]) = ac0;
    }
    if (sb < S) {
      const size_t idx = (size_t)(b * S + sb) * HID + h * DH + dg * 4;
      *reinterpret_cast<float4*>(&mean_ctx[idx]) = am1;
      *reinterpret_cast<float4*>(&cov_ctx[idx]) = ac1;
    }
  }
}

extern "C" void kernel_launch(void* const* d_in, const int* in_sizes, int n_in,
                              void* d_out, int out_size, void* d_ws, size_t ws_size,
                              hipStream_t stream) {
  const float* in_mean = (const float*)d_in[0];
  const float* in_cov = (const float*)d_in[1];
  const float* Wmq = (const float*)d_in[2];
  const float* bmq = (const float*)d_in[3];
  const float* Wcq = (const float*)d_in[4];
  const float* bcq = (const float*)d_in[5];
  const float* Wmk = (const float*)d_in[6];
  const float* bmk = (const float*)d_in[7];
  const float* Wck = (const float*)d_in[8];
  const float* bck = (const float*)d_in[9];
  const float* Wmv = (const float*)d_in[10];
  const float* bmv = (const float*)d_in[11];
  const float* Wcv = (const float*)d_in[12];
  const float* bcv = (const float*)d_in[13];
  const float* Wmd = (const float*)d_in[14];
  const float* bmd = (const float*)d_in[15];
  const float* Wcd = (const float*)d_in[16];
  const float* bcd = (const float*)d_in[17];

  const size_t NP = (size_t)M * HID;  // 9,682,944
  const size_t need = 6 * NP * sizeof(__hip_bfloat16) +
                      4 * (size_t)BNS * sizeof(float) + 2 * NP * sizeof(float);
  if (ws_size < need) return;  // fail loudly (output stays zero)

  __hip_bfloat16* mq = (__hip_bfloat16*)d_ws;
  __hip_bfloat16* mk = mq + NP;
  __hip_bfloat16* mv = mq + 2 * NP;
  __hip_bfloat16* cq = mq + 3 * NP;
  __hip_bfloat16* ck = mq + 4 * NP;
  __hip_bfloat16* cv = mq + 5 * NP;
  float* m2q = (float*)(mq + 6 * NP);
  float* cqsum = m2q + BNS;
  float* m2k = m2q + 2 * (size_t)BNS;
  float* cksum = m2q + 3 * (size_t)BNS;
  float* mean_ctx = m2q + 4 * (size_t)BNS;
  float* cov_ctx = mean_ctx + NP;

  float* out_mean = (float*)d_out;
  float* out_cov = out_mean + NP;

  dim3 blk(256);
  dim3 gg(M / 64, HID / 64);  // (197, 12)

  gemm_kernel<0, 1><<<gg, blk, 0, stream>>>(in_mean, Wmq, bmq, mq);
  gemm_kernel<0, 1><<<gg, blk, 0, stream>>>(in_mean, Wmk, bmk, mk);
  gemm_kernel<0, 1><<<gg, blk, 0, stream>>>(in_mean, Wmv, bmv, mv);
  gemm_kernel<1, 1><<<gg, blk, 0, stream>>>(in_cov, Wcq, bcq, cq);
  gemm_kernel<1, 1><<<gg, blk, 0, stream>>>(in_cov, Wck, bck, ck);
  gemm_kernel<1, 1><<<gg, blk, 0, stream>>>(in_cov, Wcv, bcv, cv);

  sums_kernel<<<BNS / 4, blk, 0, stream>>>(mq, cq, mk, ck, m2q, cqsum, m2k, cksum);

  attn_kernel<<<dim3((S + 31) / 32, NH, B), blk, 0, stream>>>(
      mq, cq, mk, ck, mv, cv, m2q, cqsum, m2k, cksum, mean_ctx, cov_ctx);

  gemm_kernel<0, 0><<<gg, blk, 0, stream>>>(mean_ctx, Wmd, bmd, out_mean);
  gemm_kernel<0, 0><<<gg, blk, 0, stream>>>(cov_ctx, Wcd, bcd, out_cov);
}

// Round 2
// 416.692 us; speedup vs baseline: 8.4160x; 8.4160x over previous
//
#include <hip/hip_runtime.h>
#include <hip/hip_bf16.h>

typedef _Float16 f16;
typedef _Float16 f16x8 __attribute__((ext_vector_type(8)));
typedef float f32x4 __attribute__((ext_vector_type(4)));

constexpr int B = 64, S = 197, HID = 768, NH = 12, DH = 64;
constexpr int M = B * S;      // 12608
constexpr int Mpad = 12672;   // 99 * 128
constexpr int BNS = B * NH * S;

__device__ inline f32x4 mfma16(f16x8 a, f16x8 b, f32x4 c) {
  return __builtin_amdgcn_mfma_f32_16x16x32_f16(a, b, c, 0, 0, 0);
}

// ---------------- pre-pass: f32 -> f16 (padded, zero tail) ----------------
__global__ __launch_bounds__(256) void cvt_x_kernel(
    const float* __restrict__ xm, const float* __restrict__ xc,
    f16* __restrict__ ym, f16* __restrict__ yc) {
  const size_t i8 = ((size_t)blockIdx.x * 256 + threadIdx.x) * 8;
  f16x8 vm = {}, vc = {};
  if (i8 < (size_t)M * HID) {
    const float4 a0 = *reinterpret_cast<const float4*>(xm + i8);
    const float4 a1 = *reinterpret_cast<const float4*>(xm + i8 + 4);
    const float4 b0 = *reinterpret_cast<const float4*>(xc + i8);
    const float4 b1 = *reinterpret_cast<const float4*>(xc + i8 + 4);
    vm[0] = (f16)a0.x; vm[1] = (f16)a0.y; vm[2] = (f16)a0.z; vm[3] = (f16)a0.w;
    vm[4] = (f16)a1.x; vm[5] = (f16)a1.y; vm[6] = (f16)a1.z; vm[7] = (f16)a1.w;
    vc[0] = (f16)b0.x; vc[1] = (f16)b0.y; vc[2] = (f16)b0.z; vc[3] = (f16)b0.w;
    vc[4] = (f16)b1.x; vc[5] = (f16)b1.y; vc[6] = (f16)b1.z; vc[7] = (f16)b1.w;
  }
  *reinterpret_cast<f16x8*>(ym + i8) = vm;
  *reinterpret_cast<f16x8*>(yc + i8) = vc;
}

// ---------------- pre-pass: W [k][n] f32 -> Wt [n][k] f16 -----------------
struct WPtrs { const float* w[8]; };

__global__ __launch_bounds__(256) void cvt_w_kernel(WPtrs p, f16* __restrict__ wt) {
  __shared__ float tile[32][33];
  const int z = blockIdx.z;
  const float* W = p.w[z];
  f16* Wt = wt + (size_t)z * HID * HID;
  const int k0 = blockIdx.x * 32, n0 = blockIdx.y * 32;
  const int tx = threadIdx.x & 31, ty = threadIdx.x >> 5;  // ty 0..7
#pragma unroll
  for (int i = 0; i < 4; ++i)
    tile[ty + i * 8][tx] = W[(size_t)(k0 + ty + i * 8) * HID + n0 + tx];
  __syncthreads();
#pragma unroll
  for (int i = 0; i < 4; ++i)
    Wt[(size_t)(n0 + ty + i * 8) * HID + k0 + tx] = (f16)tile[tx][ty + i * 8];
}

// ---------------- f16 MFMA GEMM: Y = act(A @ Wt^T + bias) -----------------
// A: [Mpad][768] f16; Bt: [(Nblocks*128)][768] f16 (n-major)
// MODE 0: 3 f16 outputs (mean proj); MODE 1: 3 f16 outputs, sqrt for sel<2 (cov proj)
// MODE 2: single f32 output, rows guarded to M
struct GemmArgs {
  const f16* A; const f16* Bt;
  void* y0; void* y1; void* y2;
  const float* b0; const float* b1; const float* b2;
};

template <int MODE>
__global__ __launch_bounds__(256, 2) void gemm_kernel(GemmArgs g) {
  __shared__ alignas(16) f16 As[128 * 64];
  __shared__ alignas(16) f16 Bs[128 * 64];
  const int tid = threadIdx.x;
  const int w = tid >> 6, lane = tid & 63;
  const int l15 = lane & 15, lg = lane >> 4;
  const int m0 = blockIdx.x * 128, n0 = blockIdx.y * 128;
  const int wr = (w >> 1) * 64, wc = (w & 1) * 64;

  // staging: thread covers row sr = tid>>1, col-half sh
  const int sr = tid >> 1, sh = (tid & 1) * 32;
  const f16* gA = g.A + (size_t)(m0 + sr) * HID + sh;
  const f16* gB = g.Bt + (size_t)(n0 + sr) * HID + sh;

  f16x8 ra[4], rb[4];
#pragma unroll
  for (int j = 0; j < 4; ++j) {
    ra[j] = *reinterpret_cast<const f16x8*>(gA + j * 8);
    rb[j] = *reinterpret_cast<const f16x8*>(gB + j * 8);
  }

  f32x4 acc[4][4] = {};

  const int arow = wr + l15;
  const int brow = wc + l15;
  const int kb = lg * 16;

  for (int kt = 0; kt < 12; ++kt) {
    __syncthreads();  // previous tile's reads done
    {
      const int wb = sr * 128;
      const int xr = (sr & 7) << 4;
#pragma unroll
      for (int j = 0; j < 4; ++j) {
        const int cb = ((sh * 2) + j * 16) ^ xr;
        *reinterpret_cast<f16x8*>(reinterpret_cast<char*>(As) + wb + cb) = ra[j];
        *reinterpret_cast<f16x8*>(reinterpret_cast<char*>(Bs) + wb + cb) = rb[j];
      }
    }
    __syncthreads();
    if (kt + 1 < 12) {
      const int ko = (kt + 1) * 64;
#pragma unroll
      for (int j = 0; j < 4; ++j) {
        ra[j] = *reinterpret_cast<const f16x8*>(gA + ko + j * 8);
        rb[j] = *reinterpret_cast<const f16x8*>(gB + ko + j * 8);
      }
    }
#pragma unroll
    for (int ks = 0; ks < 2; ++ks) {
      f16x8 af[4], bf[4];
#pragma unroll
      for (int fi = 0; fi < 4; ++fi) {
        const int row = arow + fi * 16;
        af[fi] = *reinterpret_cast<const f16x8*>(
            reinterpret_cast<char*>(As) + row * 128 + ((ks * 64 + kb) ^ ((row & 7) << 4)));
      }
#pragma unroll
      for (int fj = 0; fj < 4; ++fj) {
        const int row = brow + fj * 16;
        bf[fj] = *reinterpret_cast<const f16x8*>(
            reinterpret_cast<char*>(Bs) + row * 128 + ((ks * 64 + kb) ^ ((row & 7) << 4)));
      }
#pragma unroll
      for (int fi = 0; fi < 4; ++fi)
#pragma unroll
        for (int fj = 0; fj < 4; ++fj)
          acc[fi][fj] = mfma16(af[fi], bf[fj], acc[fi][fj]);
    }
  }

  // epilogue
  const int nsel = (MODE < 2) ? (n0 / 768) : 0;
  const int ncol0 = n0 - nsel * 768 + wc;
  const float* bias = (nsel == 0) ? g.b0 : (nsel == 1 ? g.b1 : g.b2);
  const int rbase = m0 + wr + lg * 4;
  const int cbase = ncol0 + l15;
  f16* Yh = reinterpret_cast<f16*>(nsel == 0 ? g.y0 : (nsel == 1 ? g.y1 : g.y2));
#pragma unroll
  for (int fj = 0; fj < 4; ++fj) {
    const int col = cbase + fj * 16;
    const float bv = bias[col];
#pragma unroll
    for (int fi = 0; fi < 4; ++fi) {
#pragma unroll
      for (int r = 0; r < 4; ++r) {
        const int row = rbase + fi * 16 + r;
        float v = acc[fi][fj][r] + bv;
        if (MODE == 1) v = (v > 0.f) ? v + 1.f : __expf(v);
        if (MODE == 2) {
          if (row < M) reinterpret_cast<float*>(g.y0)[(size_t)row * HID + col] = v;
        } else {
          f16 sv = (MODE == 1 && nsel < 2) ? (f16)sqrtf(v) : (f16)v;
          Yh[(size_t)row * HID + col] = sv;
        }
      }
    }
  }
}

// -------- per-(b,h,s) terms: qterm = sum(m^2)+sum(s^2) (s=sqrt(c)) --------
__global__ __launch_bounds__(256) void sums_kernel(
    const f16* __restrict__ mq, const f16* __restrict__ sq,
    const f16* __restrict__ mk, const f16* __restrict__ sk,
    float* __restrict__ qterm, float* __restrict__ kterm) {
  const int w = threadIdx.x >> 6, lane = threadIdx.x & 63;
  const int t = blockIdx.x * 4 + w;
  const int b = t / (NH * S);
  const int rem = t - b * (NH * S);
  const int h = rem / S;
  const int s = rem - h * S;
  const size_t idx = (size_t)(b * S + s) * HID + h * DH + lane;
  const float a1 = (float)mq[idx], a2 = (float)sq[idx];
  const float a3 = (float)mk[idx], a4 = (float)sk[idx];
  float vq = a1 * a1 + a2 * a2;
  float vk = a3 * a3 + a4 * a4;
#pragma unroll
  for (int off = 32; off; off >>= 1) {
    vq += __shfl_down(vq, off, 64);
    vk += __shfl_down(vk, off, 64);
  }
  if (lane == 0) { qterm[t] = vq; kterm[t] = vk; }
}

// ---------------- fused Wasserstein attention (f16 MFMA) ------------------
// block = (b, h, 64-row Q tile); 256 threads = 4 waves; wave w owns score
// cols [w*64, w*64+64) and PV d-cols [w*16, w*16+16)
__global__ __launch_bounds__(256, 2) void attn_kernel(
    const f16* __restrict__ mq, const f16* __restrict__ sq,
    const f16* __restrict__ mk, const f16* __restrict__ sk,
    const f16* __restrict__ mv, const f16* __restrict__ cv,
    const float* __restrict__ qterm, const float* __restrict__ kterm,
    f16* __restrict__ mean_ctx, f16* __restrict__ cov_ctx) {
  __shared__ alignas(16) f16 Vt[64 * 256];  // [d][j], swizzled
  __shared__ alignas(16) f16 P[64 * 256];   // [q][j] unnormalized exp, swizzled
  __shared__ float qt_s[64];
  __shared__ float kt_s[256];
  __shared__ float red_m[4][64];
  __shared__ float red_s[4][64];

  const int b = blockIdx.z, h = blockIdx.y, s0 = blockIdx.x * 64;
  const int tid = threadIdx.x, w = tid >> 6;
  const int lane = tid & 63, l15 = lane & 15, lg = lane >> 4;

  const size_t base = (size_t)(b * S) * HID + h * DH;
  const int tbase = (b * NH + h) * S;

  if (tid < 64) {
    const int s = s0 + tid;
    qt_s[tid] = (s < S) ? qterm[tbase + s] : 0.f;
  }
  kt_s[tid] = (tid < S) ? kterm[tbase + tid] : 0.f;
  __syncthreads();  // A

  // V(mean) rows for transpose staging: thread owns column j = tid
  f16x8 vstage[8];
  {
    const size_t o = base + (size_t)tid * HID;
#pragma unroll
    for (int e8 = 0; e8 < 8; ++e8)
      vstage[e8] = *reinterpret_cast<const f16x8*>(mv + o + e8 * 8);
  }
  // Q fragments in registers: row = s0 + fi*16 + l15, k = ks*32 + lg*8
  f16x8 qm[4][2], qs_[4][2];
#pragma unroll
  for (int fi = 0; fi < 4; ++fi) {
    const size_t o = base + (size_t)(s0 + fi * 16 + l15) * HID + lg * 8;
    qm[fi][0] = *reinterpret_cast<const f16x8*>(mq + o);
    qm[fi][1] = *reinterpret_cast<const f16x8*>(mq + o + 32);
    qs_[fi][0] = *reinterpret_cast<const f16x8*>(sq + o);
    qs_[fi][1] = *reinterpret_cast<const f16x8*>(sq + o + 32);
  }

  // ---- scores: acc[fi][fj] over 2 matrices ----
  f32x4 acc[4][4] = {};
#pragma unroll
  for (int fj = 0; fj < 4; ++fj) {
    const size_t o = base + (size_t)(w * 64 + fj * 16 + l15) * HID + lg * 8;
    const f16x8 km0 = *reinterpret_cast<const f16x8*>(mk + o);
    const f16x8 km1 = *reinterpret_cast<const f16x8*>(mk + o + 32);
    const f16x8 kf0 = *reinterpret_cast<const f16x8*>(sk + o);
    const f16x8 kf1 = *reinterpret_cast<const f16x8*>(sk + o + 32);
#pragma unroll
    for (int fi = 0; fi < 4; ++fi) {
      acc[fi][fj] = mfma16(qm[fi][0], km0, acc[fi][fj]);
      acc[fi][fj] = mfma16(qs_[fi][0], kf0, acc[fi][fj]);
      acc[fi][fj] = mfma16(qm[fi][1], km1, acc[fi][fj]);
      acc[fi][fj] = mfma16(qs_[fi][1], kf1, acc[fi][fj]);
    }
  }

  // ---- transform to scores + row max ----
#pragma unroll
  for (int fi = 0; fi < 4; ++fi) {
#pragma unroll
    for (int r = 0; r < 4; ++r) {
      const int i = fi * 16 + lg * 4 + r;
      const float qv = qt_s[i];
      float mx = -1e30f;
#pragma unroll
      for (int fj = 0; fj < 4; ++fj) {
        const int j = w * 64 + fj * 16 + l15;
        float sv = 0.25f * acc[fi][fj][r] - 0.125f * (qv + kt_s[j]);
        if (j >= S) sv = -1e30f;
        acc[fi][fj][r] = sv;
        mx = fmaxf(mx, sv);
      }
      mx = fmaxf(mx, __shfl_xor(mx, 1, 64));
      mx = fmaxf(mx, __shfl_xor(mx, 2, 64));
      mx = fmaxf(mx, __shfl_xor(mx, 4, 64));
      mx = fmaxf(mx, __shfl_xor(mx, 8, 64));
      if (l15 == 0) red_m[w][i] = mx;
    }
  }
  __syncthreads();  // B

  // ---- exp (unnormalized) -> P LDS; row sums; stage Vt(mean) ----
#pragma unroll
  for (int fi = 0; fi < 4; ++fi) {
#pragma unroll
    for (int r = 0; r < 4; ++r) {
      const int i = fi * 16 + lg * 4 + r;
      const float m = fmaxf(fmaxf(red_m[0][i], red_m[1][i]),
                            fmaxf(red_m[2][i], red_m[3][i]));
      float sum = 0.f;
#pragma unroll
      for (int fj = 0; fj < 4; ++fj) {
        const int j = w * 64 + fj * 16 + l15;
        const float e = __expf(acc[fi][fj][r] - m);
        sum += e;
        *reinterpret_cast<f16*>(reinterpret_cast<char*>(P) + i * 512 +
                                ((2 * j) ^ ((i & 7) << 4))) = (f16)e;
      }
      sum += __shfl_xor(sum, 1, 64);
      sum += __shfl_xor(sum, 2, 64);
      sum += __shfl_xor(sum, 4, 64);
      sum += __shfl_xor(sum, 8, 64);
      if (l15 == 0) red_s[w][i] = sum;
    }
  }
#pragma unroll
  for (int e8 = 0; e8 < 8; ++e8) {
#pragma unroll
    for (int e = 0; e < 8; ++e) {
      const int d = e8 * 8 + e;
      *reinterpret_cast<f16*>(reinterpret_cast<char*>(Vt) + d * 512 +
                              ((2 * tid) ^ ((d & 7) << 4))) = vstage[e8][e];
    }
  }
  __syncthreads();  // C

  // issue cov-V loads early (hide under PV-mean)
  f16x8 vcstage[8];
  {
    const size_t o = base + (size_t)tid * HID;
#pragma unroll
    for (int e8 = 0; e8 < 8; ++e8)
      vcstage[e8] = *reinterpret_cast<const f16x8*>(cv + o + e8 * 8);
  }
  float invq[4][4];
#pragma unroll
  for (int fi = 0; fi < 4; ++fi)
#pragma unroll
    for (int r = 0; r < 4; ++r) {
      const int i = fi * 16 + lg * 4 + r;
      invq[fi][r] = 1.0f / (red_s[0][i] + red_s[1][i] + red_s[2][i] + red_s[3][i]);
    }

  // ---- PV mean ----
  const int d = w * 16 + l15;
  f32x4 pacc[4] = {};
#pragma unroll
  for (int ks = 0; ks < 8; ++ks) {
    const f16x8 vb = *reinterpret_cast<const f16x8*>(
        reinterpret_cast<char*>(Vt) + d * 512 + ((ks * 64 + lg * 16) ^ ((d & 7) << 4)));
#pragma unroll
    for (int fi = 0; fi < 4; ++fi) {
      const int q = fi * 16 + l15;
      const f16x8 pa = *reinterpret_cast<const f16x8*>(
          reinterpret_cast<char*>(P) + q * 512 + ((ks * 64 + lg * 16) ^ ((q & 7) << 4)));
      pacc[fi] = mfma16(pa, vb, pacc[fi]);
    }
  }
#pragma unroll
  for (int fi = 0; fi < 4; ++fi) {
#pragma unroll
    for (int r = 0; r < 4; ++r) {
      const int srow = s0 + fi * 16 + lg * 4 + r;
      if (srow < S)
        mean_ctx[(size_t)(b * S + srow) * HID + h * DH + d] =
            (f16)(pacc[fi][r] * invq[fi][r]);
    }
  }
  __syncthreads();  // D: Vt(mean) reads done

  // ---- stage Vt(cov) ----
#pragma unroll
  for (int e8 = 0; e8 < 8; ++e8) {
#pragma unroll
    for (int e = 0; e < 8; ++e) {
      const int dd = e8 * 8 + e;
      *reinterpret_cast<f16*>(reinterpret_cast<char*>(Vt) + dd * 512 +
                              ((2 * tid) ^ ((dd & 7) << 4))) = vcstage[e8][e];
    }
  }
  __syncthreads();  // E

  // ---- PV cov with squared P ----
  f32x4 cacc[4] = {};
#pragma unroll
  for (int ks = 0; ks < 8; ++ks) {
    const f16x8 vb = *reinterpret_cast<const f16x8*>(
        reinterpret_cast<char*>(Vt) + d * 512 + ((ks * 64 + lg * 16) ^ ((d & 7) << 4)));
#pragma unroll
    for (int fi = 0; fi < 4; ++fi) {
      const int q = fi * 16 + l15;
      f16x8 pa = *reinterpret_cast<const f16x8*>(
          reinterpret_cast<char*>(P) + q * 512 + ((ks * 64 + lg * 16) ^ ((q & 7) << 4)));
      pa = pa * pa;
      cacc[fi] = mfma16(pa, vb, cacc[fi]);
    }
  }
#pragma unroll
  for (int fi = 0; fi < 4; ++fi) {
#pragma unroll
    for (int r = 0; r < 4; ++r) {
      const int srow = s0 + fi * 16 + lg * 4 + r;
      if (srow < S)
        cov_ctx[(size_t)(b * S + srow) * HID + h * DH + d] =
            (f16)(cacc[fi][r] * invq[fi][r] * invq[fi][r]);
    }
  }
}

extern "C" void kernel_launch(void* const* d_in, const int* in_sizes, int n_in,
                              void* d_out, int out_size, void* d_ws, size_t ws_size,
                              hipStream_t stream) {
  const float* in_mean = (const float*)d_in[0];
  const float* in_cov = (const float*)d_in[1];
  const float* Wmq = (const float*)d_in[2];  const float* bmq = (const float*)d_in[3];
  const float* Wcq = (const float*)d_in[4];  const float* bcq = (const float*)d_in[5];
  const float* Wmk = (const float*)d_in[6];  const float* bmk = (const float*)d_in[7];
  const float* Wck = (const float*)d_in[8];  const float* bck = (const float*)d_in[9];
  const float* Wmv = (const float*)d_in[10]; const float* bmv = (const float*)d_in[11];
  const float* Wcv = (const float*)d_in[12]; const float* bcv = (const float*)d_in[13];
  const float* Wmd = (const float*)d_in[14]; const float* bmd = (const float*)d_in[15];
  const float* Wcd = (const float*)d_in[16]; const float* bcd = (const float*)d_in[17];

  const size_t NPH = (size_t)Mpad * HID;      // 9,732,096
  const size_t WSZ = (size_t)8 * HID * HID;   // 4,718,592
  const size_t need = (8 * NPH + WSZ) * sizeof(f16) + 2 * (size_t)BNS * sizeof(float);
  if (ws_size < need) return;

  f16* Xm = (f16*)d_ws;           // later: mean_ctx
  f16* Xc = Xm + NPH;             // later: cov_ctx
  f16* Wt = Xc + NPH;             // 8 matrices [out][in]
  f16* mq = Wt + WSZ;
  f16* mk = mq + NPH;
  f16* mv = mk + NPH;
  f16* sqb = mv + NPH;
  f16* skb = sqb + NPH;
  f16* cvb = skb + NPH;
  float* qterm = (float*)(cvb + NPH);
  float* kterm = qterm + BNS;
  f16* mean_ctx = Xm;
  f16* cov_ctx = Xc;

  float* out_mean = (float*)d_out;
  float* out_cov = out_mean + (size_t)M * HID;

  dim3 blk(256);

  cvt_x_kernel<<<(Mpad * HID) / (256 * 8), blk, 0, stream>>>(in_mean, in_cov, Xm, Xc);

  WPtrs wp;
  wp.w[0] = Wmq; wp.w[1] = Wmk; wp.w[2] = Wmv;
  wp.w[3] = Wcq; wp.w[4] = Wck; wp.w[5] = Wcv;
  wp.w[6] = Wmd; wp.w[7] = Wcd;
  cvt_w_kernel<<<dim3(HID / 32, HID / 32, 8), blk, 0, stream>>>(wp, Wt);

  GemmArgs gm; gm.A = Xm; gm.Bt = Wt;
  gm.y0 = mq; gm.y1 = mk; gm.y2 = mv; gm.b0 = bmq; gm.b1 = bmk; gm.b2 = bmv;
  gemm_kernel<0><<<dim3(Mpad / 128, 18), blk, 0, stream>>>(gm);

  GemmArgs gc; gc.A = Xc; gc.Bt = Wt + (size_t)3 * HID * HID;
  gc.y0 = sqb; gc.y1 = skb; gc.y2 = cvb; gc.b0 = bcq; gc.b1 = bck; gc.b2 = bcv;
  gemm_kernel<1><<<dim3(Mpad / 128, 18), blk, 0, stream>>>(gc);

  sums_kernel<<<BNS / 4, blk, 0, stream>>>(mq, sqb, mk, skb, qterm, kterm);

  attn_kernel<<<dim3(4, NH, B), blk, 0, stream>>>(mq, sqb, mk, skb, mv, cvb,
                                                  qterm, kterm, mean_ctx, cov_ctx);

  GemmArgs g1; g1.A = mean_ctx; g1.Bt = Wt + (size_t)6 * HID * HID;
  g1.y0 = out_mean; g1.y1 = nullptr; g1.y2 = nullptr;
  g1.b0 = bmd; g1.b1 = nullptr; g1.b2 = nullptr;
  gemm_kernel<2><<<dim3(Mpad / 128, 6), blk, 0, stream>>>(g1);

  GemmArgs g2; g2.A = cov_ctx; g2.Bt = Wt + (size_t)7 * HID * HID;
  g2.y0 = out_cov; g2.y1 = nullptr; g2.y2 = nullptr;
  g2.b0 = bcd; g2.b1 = nullptr; g2.b2 = nullptr;
  gemm_kernel<2><<<dim3(Mpad / 128, 6), blk, 0, stream>>>(g2);
}